// Round 6
// baseline (660.399 us; speedup 1.0000x reference)
//
#include <hip/hip_runtime.h>
#include <math.h>

// Problem constants (from reference): B=16, Lq=Lk=256, Dk=64, D_MODEL=512
namespace {

constexpr int L = 256;
constexpr int D = 64;
constexpr float INV_TEMPER = 0.04419417382415922f;  // 1/sqrt(512)

// One block per (b, q) row. 256 threads = 16 groups x 16 lanes.
//   lane4 = t & 15 : owns d-quad [4*lane4, 4*lane4+4)
//   grp   = t >> 4 : k-row group; at iter `it` handles k = it*16 + grp
// Every pos_emb access is a contiguous 256B segment per k-row, coalesced
// across the 16 lanes of the group (float4 per lane). Masked rows (mask!=0)
// skip the k_pos load; zero-weight rows skip the v_pos load — that is the
// main BW lever (~30% of the 512 MiB pos_emb stream each).
__global__ __launch_bounds__(256, 4)
void sdpa_fused(const float* __restrict__ Q,        // [B][L][D]
                const float* __restrict__ K,        // [B][L][D]
                const float* __restrict__ V,        // [B][L][D]
                const int*   __restrict__ MASK,     // [B][L][L]  nonzero = masked
                const float* __restrict__ POS,      // [B][L][L][2*D]
                float* __restrict__ OUT,            // [B][L][D]
                float* __restrict__ OUT_ATTN)       // [B][L][L]
{
    const int bq    = blockIdx.x;        // b*256 + qi
    const int b     = bq >> 8;
    const int t     = threadIdx.x;       // 0..255
    const int lane4 = t & 15;
    const int grp   = t >> 4;

    __shared__ float q_sh[D];
    __shared__ int   m_sh[L];
    __shared__ float p_sh[L];
    __shared__ float red_sh[16][D + 1];  // +1 pad: break bank aliasing in tree reduce
    __shared__ float wmax[4], wsum[4];

    const float* __restrict__ posrow = POS + (size_t)bq * L * (2 * D);
    const float* __restrict__ kmat   = K + (size_t)b * L * D;
    const float* __restrict__ vmat   = V + (size_t)b * L * D;

    m_sh[t] = MASK[(size_t)bq * L + t];            // one coalesced 1KB load
    if (t < D) q_sh[t] = Q[(size_t)bq * D + t];
    __syncthreads();

    const float4 qv = *reinterpret_cast<const float4*>(&q_sh[lane4 * 4]);

    // ---------------- Phase 1: scores = (q.k + q.kpos) / temper, masked ----
    #pragma unroll 4
    for (int it = 0; it < 16; ++it) {
        const int kk = it * 16 + grp;
        const int m  = m_sh[kk];                   // uniform across the 16-lane group
        float s = -INFINITY;
        if (m == 0) {                              // masked rows: skip ALL loads
            const float4 kv = *reinterpret_cast<const float4*>(kmat + kk * D + lane4 * 4);
            const float4 pe = *reinterpret_cast<const float4*>(posrow + (size_t)kk * (2 * D) + lane4 * 4);
            float part = qv.x * (kv.x + pe.x) + qv.y * (kv.y + pe.y)
                       + qv.z * (kv.z + pe.z) + qv.w * (kv.w + pe.w);
            // reduce across the 16-lane group (stays inside the cluster)
            part += __shfl_xor(part, 1);
            part += __shfl_xor(part, 2);
            part += __shfl_xor(part, 4);
            part += __shfl_xor(part, 8);
            s = part * INV_TEMPER;
        }
        if (lane4 == 0) p_sh[kk] = s;
    }
    __syncthreads();

    // ---------------- Phase 2: softmax over k (256 entries, 1 per thread) --
    const float sv = p_sh[t];
    float mx = sv;
    #pragma unroll
    for (int off = 1; off < 64; off <<= 1) mx = fmaxf(mx, __shfl_xor(mx, off));
    const int wid = t >> 6;
    if ((t & 63) == 0) wmax[wid] = mx;
    __syncthreads();
    mx = fmaxf(fmaxf(wmax[0], wmax[1]), fmaxf(wmax[2], wmax[3]));

    // all-masked row => mx = -inf => reference outputs zeros (NaN->0)
    float e = (mx == -INFINITY) ? 0.0f : __expf(sv - mx);
    float sm = e;
    #pragma unroll
    for (int off = 1; off < 64; off <<= 1) sm += __shfl_xor(sm, off);
    if ((t & 63) == 0) wsum[wid] = sm;
    __syncthreads();
    sm = wsum[0] + wsum[1] + wsum[2] + wsum[3];

    const float p = (sm > 0.0f) ? e / sm : 0.0f;
    OUT_ATTN[(size_t)bq * L + t] = p;              // coalesced 1KB store per block
    p_sh[t] = p;                                   // all reads of p_sh happened pre-wmax barrier
    __syncthreads();

    // ---------------- Phase 3: out = sum_k p_k * (v_k + vpos_k) ------------
    float4 acc = make_float4(0.0f, 0.0f, 0.0f, 0.0f);
    #pragma unroll 4
    for (int it = 0; it < 16; ++it) {
        const int kk = it * 16 + grp;
        const float pk = p_sh[kk];                 // uniform across the group
        if (pk != 0.0f) {                          // skip vpos load for zero-weight rows
            const float4 vv = *reinterpret_cast<const float4*>(vmat + kk * D + lane4 * 4);
            const float4 pe = *reinterpret_cast<const float4*>(posrow + (size_t)kk * (2 * D) + D + lane4 * 4);
            acc.x = fmaf(pk, vv.x + pe.x, acc.x);
            acc.y = fmaf(pk, vv.y + pe.y, acc.y);
            acc.z = fmaf(pk, vv.z + pe.z, acc.z);
            acc.w = fmaf(pk, vv.w + pe.w, acc.w);
        }
    }

    // reduce the 16 k-groups
    red_sh[grp][lane4 * 4 + 0] = acc.x;
    red_sh[grp][lane4 * 4 + 1] = acc.y;
    red_sh[grp][lane4 * 4 + 2] = acc.z;
    red_sh[grp][lane4 * 4 + 3] = acc.w;
    __syncthreads();
    #pragma unroll
    for (int s = 8; s > 0; s >>= 1) {
        if (grp < s) {
            #pragma unroll
            for (int j = 0; j < 4; ++j)
                red_sh[grp][lane4 * 4 + j] += red_sh[grp + s][lane4 * 4 + j];
        }
        __syncthreads();
    }
    if (t < D) OUT[(size_t)bq * D + t] = red_sh[0][t];
}

} // namespace

extern "C" void kernel_launch(void* const* d_in, const int* in_sizes, int n_in,
                              void* d_out, int out_size, void* d_ws, size_t ws_size,
                              hipStream_t stream) {
    (void)in_sizes; (void)n_in; (void)d_ws; (void)ws_size; (void)out_size;
    const float* q    = (const float*)d_in[0];
    const float* k    = (const float*)d_in[1];
    const float* v    = (const float*)d_in[2];
    const int*   mask = (const int*)d_in[3];
    const float* pos  = (const float*)d_in[4];

    float* out      = (float*)d_out;                         // [16][256][64]
    float* out_attn = out + (size_t)16 * 256 * 64;           // [16][256][256]

    sdpa_fused<<<dim3(16 * 256), dim3(256), 0, stream>>>(
        q, k, v, mask, pos, out, out_attn);
}